// Round 10
// baseline (3051.854 us; speedup 1.0000x reference)
//
#include <hip/hip_runtime.h>

#define B_ 512
#define L_ 1000
#define H_ 128
#define G_ 512  // 4*H

typedef _Float16 v8h __attribute__((ext_vector_type(8)));
typedef _Float16 h2t __attribute__((ext_vector_type(2)));
typedef float v4f __attribute__((ext_vector_type(4)));

__device__ __forceinline__ float sigmoid_f(float x) {
  return __builtin_amdgcn_rcpf(1.0f + __builtin_amdgcn_exp2f(-1.4426950408889634f * x));
}
__device__ __forceinline__ float tanh_f(float x) {
  return 1.0f - 2.0f * __builtin_amdgcn_rcpf(1.0f + __builtin_amdgcn_exp2f(2.8853900817779268f * x));
}

// h storage in B-FRAGMENT ORDER (round-7, verified): chunk (kt, quad, row) at
// byte kt*144 + quad*32 + row*16 holds h_row[kt*32 + quad*8 + j]. C-phase
// b128 reads: banks (8quad + 4row) mod 32 -> 32 banks, ONE address each ->
// conflict-free broadcast.
#define FB_KT 144

// gbuf padding: gate g lives at dword g + 4*(g>>5) (row = 576 dwords).
// U-phase float2 reads (lanes l,l+16,l+32,l+48 -> banks 2l+{0,4,8,12}) drop
// from 4-way to 2-addr/bank (free, m136). C-phase v4f stores at dword
// 36*wv + 4*quad (+16) stay 16B-aligned.
#define GROW 576

#define MFMA16(a, b, c) __builtin_amdgcn_mfma_f32_16x16x32_f16((a), (b), (c), 0, 0, 0)

// 256 blocks x 1024 threads (16 waves), one block/CU, 2 batch rows/block.
// Wave w holds f16 A-fragments of gates [32w,32w+32) of w_hh1, w_ih2, w_hh2
// = 96 dwords/thread (AGPR-resident). Two barriers/step:
//   U:  thr 0..127:  g1 -> c1,h1(t) -> hb1   ||  thr 128..255: g2 -> c2,
//       h2(t-1) -> hb2, out(t-1) -> xlds[row][t-1]  (LDS, not global!)
//   C:  all 16 waves: gb2' = A2i@h1 + A2h@h2 ; gb1' = A1@h1
// No global ops inside the loop (round 7: per-step out store made every
// __syncthreads drain vmcnt(0) -> FETCH/WRITE 73/150 MB). Out values park in
// consumed xlds slots, flushed coalesced at the end. wx/bb/wl in registers.
// ROUND-9 FIX (still in effect): gb1 must be FULLY zeroed (both rows, all
// 1152 padded dwords) -- partial init left LDS garbage in row-1 high gates
// (absmax 2.8e-3). ROUND-10: init restructured (equivalent) after round-9's
// infra core-dump; full bounds audit found no kernel-side fault.
__global__ __launch_bounds__(1024) void lstm_mfma(
    const float* __restrict__ x,
    const float* __restrict__ w_ih1,
    const float* __restrict__ w_hh1,
    const float* __restrict__ b_ih1,
    const float* __restrict__ b_hh1,
    const float* __restrict__ w_ih2,
    const float* __restrict__ w_hh2,
    const float* __restrict__ b_ih2,
    const float* __restrict__ b_hh2,
    const float* __restrict__ w_lin,
    const float* __restrict__ b_lin,
    float* __restrict__ out)
{
  __shared__ __align__(16) float xlds[2][L_];        // x rows; recycled as out buffer
  __shared__ __align__(16) float gb1[2][GROW];       // g1 carry (padded C-layout)
  __shared__ __align__(16) float gb2[2][GROW];       // g2 raw
  __shared__ __align__(16) unsigned char hb1[4 * FB_KT];  // h1, fragment order
  __shared__ __align__(16) unsigned char hb2[4 * FB_KT];  // h2, fragment order

  const int tid   = threadIdx.x;
  const int wv    = tid >> 6;
  const int lane  = tid & 63;
  const int quad  = lane >> 4;
  const int m15   = lane & 15;
  const int r0    = blockIdx.x * 2;
  const int gbase = wv * 32;

  // ---- one-time staging ----
  for (int i = tid; i < 2 * L_; i += 1024) ((float*)xlds)[i] = x[r0 * L_ + i];
  if (tid < GROW) {            // zero BOTH rows of gb1 and gb2 (all padding)
    gb1[0][tid] = 0.f; gb1[1][tid] = 0.f;
    gb2[0][tid] = 0.f; gb2[1][tid] = 0.f;
  }
  if (tid >= GROW && tid < GROW + (4 * FB_KT) / 4) {   // hb1|hb2 zero
    const int i = tid - GROW;
    ((unsigned*)hb1)[i] = 0u;
    ((unsigned*)hb2)[i] = 0u;
  }

  // ---- hoisted loop-invariants for the update waves (registers) ----
  float2 wxv[4], bb1v[4];   // U1: w_ih1, b_ih1+b_hh1 pairs
  float2 bb2v[4], wlv;      // U2: b_ih2+b_hh2 pairs, w_lin pair
  {
    const int e = 2 * lane;
    if (tid < 128) {
#pragma unroll
      for (int g = 0; g < 4; ++g) {
        wxv[g]  = *(const float2*)(w_ih1 + 128 * g + e);
        float2 a = *(const float2*)(b_ih1 + 128 * g + e);
        float2 b = *(const float2*)(b_hh1 + 128 * g + e);
        bb1v[g] = float2{a.x + b.x, a.y + b.y};
      }
    } else if (tid < 256) {
#pragma unroll
      for (int g = 0; g < 4; ++g) {
        float2 a = *(const float2*)(b_ih2 + 128 * g + e);
        float2 b = *(const float2*)(b_hh2 + 128 * g + e);
        bb2v[g] = float2{a.x + b.x, a.y + b.y};
      }
      wlv = *(const float2*)(w_lin + e);
    }
  }
  const float blv = b_lin[0];

  // ---- per-wave weight A-fragments (f16): A[m][k], m=m15, k=quad*8+j ----
  v8h A1[2][4], A2i[2][4], A2h[2][4];
#pragma unroll
  for (int mt = 0; mt < 2; ++mt) {
    const int grow = (gbase + mt * 16 + m15) * H_;
#pragma unroll
    for (int kt = 0; kt < 4; ++kt) {
      const int koff = kt * 32 + quad * 8;
      float4 a, b;
      a = *(const float4*)(w_hh1 + grow + koff);
      b = *(const float4*)(w_hh1 + grow + koff + 4);
      A1[mt][kt] = v8h{(_Float16)a.x, (_Float16)a.y, (_Float16)a.z, (_Float16)a.w,
                       (_Float16)b.x, (_Float16)b.y, (_Float16)b.z, (_Float16)b.w};
      a = *(const float4*)(w_ih2 + grow + koff);
      b = *(const float4*)(w_ih2 + grow + koff + 4);
      A2i[mt][kt] = v8h{(_Float16)a.x, (_Float16)a.y, (_Float16)a.z, (_Float16)a.w,
                        (_Float16)b.x, (_Float16)b.y, (_Float16)b.z, (_Float16)b.w};
      a = *(const float4*)(w_hh2 + grow + koff);
      b = *(const float4*)(w_hh2 + grow + koff + 4);
      A2h[mt][kt] = v8h{(_Float16)a.x, (_Float16)a.y, (_Float16)a.z, (_Float16)a.w,
                        (_Float16)b.x, (_Float16)b.y, (_Float16)b.z, (_Float16)b.w};
    }
  }

  float c1s0 = 0.f, c1s1 = 0.f;  // layer-1 cell state (threads 0..127)
  float c2s0 = 0.f, c2s1 = 0.f;  // layer-2 cell state (threads 128..255)

  // U-thread gbuf read base: gate pair (2l, 2l+1): dword 2l + 4*(l>>4)
  const int ge  = 2 * lane + 4 * (lane >> 4);
  // h-write offset: k=2l -> kt*144 + quad'*32 + (l&3)*4 (+row*16)
  const int hwo = (lane >> 4) * FB_KT + ((lane >> 2) & 3) * 32 + (lane & 3) * 4;

  __syncthreads();

  for (int t = 0; t <= L_; ++t) {
    // ---- U-phase: U1(t) on thr 0..127 || U2(t-1) on thr 128..255 ----
    if (tid < 128) {
      if (t < L_) {
        const int row = tid >> 6;
        const float xv = xlds[row][t];
        float2 gi = *(const float2*)&gb1[row][ge];
        float2 gf = *(const float2*)&gb1[row][144 + ge];
        float2 gg = *(const float2*)&gb1[row][288 + ge];
        float2 go = *(const float2*)&gb1[row][432 + ge];
        float i0 = sigmoid_f(gi.x + wxv[0].x * xv + bb1v[0].x);
        float i1 = sigmoid_f(gi.y + wxv[0].y * xv + bb1v[0].y);
        float f0 = sigmoid_f(gf.x + wxv[1].x * xv + bb1v[1].x);
        float f1 = sigmoid_f(gf.y + wxv[1].y * xv + bb1v[1].y);
        float g0 = tanh_f(gg.x + wxv[2].x * xv + bb1v[2].x);
        float g1 = tanh_f(gg.y + wxv[2].y * xv + bb1v[2].y);
        float o0 = sigmoid_f(go.x + wxv[3].x * xv + bb1v[3].x);
        float o1 = sigmoid_f(go.y + wxv[3].y * xv + bb1v[3].y);
        c1s0 = f0 * c1s0 + i0 * g0;
        c1s1 = f1 * c1s1 + i1 * g1;
        h2t hp = h2t{(_Float16)(o0 * tanh_f(c1s0)), (_Float16)(o1 * tanh_f(c1s1))};
        *(unsigned*)(hb1 + row * 16 + hwo) = __builtin_bit_cast(unsigned, hp);
      }
    } else if (tid < 256) {
      if (t > 0) {
        const int row = (tid >> 6) & 1;
        float2 gi = *(const float2*)&gb2[row][ge];
        float2 gf = *(const float2*)&gb2[row][144 + ge];
        float2 gg = *(const float2*)&gb2[row][288 + ge];
        float2 go = *(const float2*)&gb2[row][432 + ge];
        float i0 = sigmoid_f(gi.x + bb2v[0].x);
        float i1 = sigmoid_f(gi.y + bb2v[0].y);
        float f0 = sigmoid_f(gf.x + bb2v[1].x);
        float f1 = sigmoid_f(gf.y + bb2v[1].y);
        float g0 = tanh_f(gg.x + bb2v[2].x);
        float g1 = tanh_f(gg.y + bb2v[2].y);
        float o0 = sigmoid_f(go.x + bb2v[3].x);
        float o1 = sigmoid_f(go.y + bb2v[3].y);
        c2s0 = f0 * c2s0 + i0 * g0;
        c2s1 = f1 * c2s1 + i1 * g1;
        float h0 = o0 * tanh_f(c2s0);
        float h1 = o1 * tanh_f(c2s1);
        h2t hp = h2t{(_Float16)h0, (_Float16)h1};
        *(unsigned*)(hb2 + row * 16 + hwo) = __builtin_bit_cast(unsigned, hp);
        float p = h0 * wlv.x + h1 * wlv.y;
#pragma unroll
        for (int s = 1; s < 64; s <<= 1) p += __shfl_xor(p, s, 64);
        if (lane == 0) xlds[row][t - 1] = p + blv;   // park in consumed x slot
      }
    }
    __syncthreads();

    // ---- C-phase: all 16 waves; 8 broadcast b128 reads feed 24 MFMA ----
    if (t < L_) {
      v4f accG0 = {0.f, 0.f, 0.f, 0.f}, accG1 = {0.f, 0.f, 0.f, 0.f};
      v4f accC0 = {0.f, 0.f, 0.f, 0.f}, accC1 = {0.f, 0.f, 0.f, 0.f};
      const int roff = quad * 32 + (m15 & 1) * 16;
#pragma unroll
      for (int kt = 0; kt < 4; ++kt) {
        v8h b1 = *(const v8h*)(hb1 + kt * FB_KT + roff);
        v8h b2 = *(const v8h*)(hb2 + kt * FB_KT + roff);
        accG0 = MFMA16(A2i[0][kt], b1, accG0);
        accG1 = MFMA16(A2i[1][kt], b1, accG1);
        accC0 = MFMA16(A1[0][kt],  b1, accC0);
        accC1 = MFMA16(A1[1][kt],  b1, accC1);
        accG0 = MFMA16(A2h[0][kt], b2, accG0);
        accG1 = MFMA16(A2h[1][kt], b2, accG1);
      }
      if (m15 < 2) {  // col=m15=batch row, gate=gbase+quad*4+reg (+16)
        const int sb = gbase + 4 * wv + 4 * quad;   // padded dword index
        *(v4f*)&gb2[m15][sb]      = accG0;
        *(v4f*)&gb2[m15][sb + 16] = accG1;
        *(v4f*)&gb1[m15][sb]      = accC0;
        *(v4f*)&gb1[m15][sb + 16] = accC1;
      }
    }
    __syncthreads();
  }

  // ---- coalesced output flush: xlds rows are out rows r0, r0+1 ----
  for (int i = tid; i < 2 * L_; i += 1024) out[r0 * L_ + i] = ((float*)xlds)[i];
}

extern "C" void kernel_launch(void* const* d_in, const int* in_sizes, int n_in,
                              void* d_out, int out_size, void* d_ws, size_t ws_size,
                              hipStream_t stream) {
  const float* x     = (const float*)d_in[0];
  const float* w_ih1 = (const float*)d_in[1];
  const float* w_hh1 = (const float*)d_in[2];
  const float* b_ih1 = (const float*)d_in[3];
  const float* b_hh1 = (const float*)d_in[4];
  const float* w_ih2 = (const float*)d_in[5];
  const float* w_hh2 = (const float*)d_in[6];
  const float* b_ih2 = (const float*)d_in[7];
  const float* b_hh2 = (const float*)d_in[8];
  const float* w_lin = (const float*)d_in[9];
  const float* b_lin = (const float*)d_in[10];

  lstm_mfma<<<B_ / 2, 1024, 0, stream>>>(
      x, w_ih1, w_hh1, b_ih1, b_hh1, w_ih2, w_hh2, b_ih2, b_hh2,
      w_lin, b_lin, (float*)d_out);
}